// Round 9
// baseline (4848.779 us; speedup 1.0000x reference)
//
#include <hip/hip_runtime.h>

#define NB    256
#define BT    1024
#define BATCH 128
#define HID   512
#define XSZ   64
#define SSZ   16
#define CPAD  32                 // ints per counter slot = 128B line
#define SPIN_MAX (1 << 17)

typedef unsigned int uint;
typedef unsigned long long ulong64;
typedef _Float16 half2v __attribute__((ext_vector_type(2)));

// agent-scope relaxed atomic load/store = sc-flagged, bypass stale L1/L2, no fences
#define AL8(p)    __hip_atomic_load((const ulong64*)(p), __ATOMIC_RELAXED, __HIP_MEMORY_SCOPE_AGENT)
#define AS4(p, v) __hip_atomic_store((uint*)(p), (v), __ATOMIC_RELAXED, __HIP_MEMORY_SCOPE_AGENT)

// ---------------- persistent device state ----------------
// act layout: [q][b] uint4, q = kpair/4 (64), b = batch (128); uint = f16 pair (cols 2m,2m+1)
__device__ __align__(16) uint4 g_h0Q[2][64 * 128];
__device__ __align__(16) uint4 g_h1Q[2][64 * 128];
__device__ __align__(16) float g_Wcomb[4 * HID * HID];   // 0.1 * W0s @ Wfc [2048][512]
__device__ int g_cnt[512 * 8 * CPAD];                    // per-phase, 8-way split counters

// ---------------- helpers ----------------
__device__ __forceinline__ float sigf(float x) { return 1.f / (1.f + __expf(-x)); }
__device__ __forceinline__ float tanh_fast(float x) {
  float ax = fabsf(x); float e = __expf(-2.f * ax);
  return copysignf((1.f - e) / (1.f + e), x);
}
__device__ __forceinline__ uint pack_f16(float a, float b) {
  half2v h; h.x = (_Float16)a; h.y = (_Float16)b;
  return __builtin_bit_cast(uint, h);
}
__device__ __forceinline__ float2 up2(uint u) {
  half2v h = __builtin_bit_cast(half2v, u);
  return make_float2((float)h.x, (float)h.y);
}
__device__ __forceinline__ float fdot2(uint a, uint w, float c) {
#if __has_builtin(__builtin_amdgcn_fdot2)
  return __builtin_amdgcn_fdot2(__builtin_bit_cast(half2v, a),
                                __builtin_bit_cast(half2v, w), c, false);
#else
  float2 av = up2(a), wv = up2(w);
  return fmaf(av.x, wv.x, fmaf(av.y, wv.y, c));
#endif
}
__device__ __forceinline__ void dot8(uint a, uint4 w0, uint4 w1, float* acc) {
  acc[0] = fdot2(a, w0.x, acc[0]); acc[1] = fdot2(a, w0.y, acc[1]);
  acc[2] = fdot2(a, w0.z, acc[2]); acc[3] = fdot2(a, w0.w, acc[3]);
  acc[4] = fdot2(a, w1.x, acc[4]); acc[5] = fdot2(a, w1.y, acc[5]);
  acc[6] = fdot2(a, w1.z, acc[6]); acc[7] = fdot2(a, w1.w, acc[7]);
}
// 16 uint4 act rows, loaded ONCE (batched coherent loads), fed to TWO weight matrices
__device__ __forceinline__ void dots16x2(const uint4* __restrict__ apq,
                                         const uint*  __restrict__ wbA,
                                         const uint*  __restrict__ wbB,
                                         float* __restrict__ accA,
                                         float* __restrict__ accB) {
  const ulong64* ap = (const ulong64*)apq;
  ulong64 lo[16], hi[16];
#pragma unroll
  for (int i = 0; i < 16; ++i) {
    lo[i] = AL8(ap + i * 256);
    hi[i] = AL8(ap + i * 256 + 1);
  }
#pragma unroll
  for (int i = 0; i < 16; ++i) {
    const uint4* wA = (const uint4*)(wbA + 32 * i);
    const uint4* wB = (const uint4*)(wbB + 32 * i);
    uint a0 = (uint)lo[i], a1 = (uint)(lo[i] >> 32);
    uint a2 = (uint)hi[i], a3 = (uint)(hi[i] >> 32);
    dot8(a0, wA[0], wA[1], accA); dot8(a0, wB[0], wB[1], accB);
    dot8(a1, wA[2], wA[3], accA); dot8(a1, wB[2], wB[3], accB);
    dot8(a2, wA[4], wA[5], accA); dot8(a2, wB[4], wB[5], accB);
    dot8(a3, wA[6], wA[7], accA); dot8(a3, wB[6], wB[7], accB);
  }
}

// poll the 8 split counter lines (lane l polls line l&7; coalesced to 8 line reqs)
__device__ __forceinline__ void cnt_wait(int pid) {
  const int l = threadIdx.x & 63;
  const int* cp = &g_cnt[(pid * 8 + (l & 7)) * CPAD];
  int guard = 0;
  for (;;) {
    int v = __hip_atomic_load(cp, __ATOMIC_RELAXED, __HIP_MEMORY_SCOPE_AGENT);
    if (__all(v >= 64)) break;     // 32 blocks/group x 2 writer waves
    __builtin_amdgcn_s_sleep(1);
    if (++guard > SPIN_MAX) break;
  }
  __builtin_amdgcn_sched_barrier(0);   // pin: no loads hoisted above the poll
}

// group wait: poller wave polls global counters, siblings spin on LDS release word
__device__ __forceinline__ void group_wait(int pid, int pw, int tid, int* rel) {
  if ((tid >> 6) == pw) {
    cnt_wait(pid);
    if ((tid & 63) == 0)
      __hip_atomic_store(&rel[pid & 1], pid, __ATOMIC_RELEASE, __HIP_MEMORY_SCOPE_WORKGROUP);
  } else {
    int guard = 0;
    while (__hip_atomic_load(&rel[pid & 1], __ATOMIC_ACQUIRE, __HIP_MEMORY_SCOPE_WORKGROUP) < pid) {
      __builtin_amdgcn_s_sleep(1);
      if (++guard > SPIN_MAX) break;
    }
    __builtin_amdgcn_sched_barrier(0);
  }
}

// ---------------- setup ----------------
__global__ void setup_kernel(float* __restrict__ out, int T) {
  int idx = blockIdx.x * blockDim.x + threadIdx.x;
  int n   = gridDim.x * blockDim.x;
  uint* z0 = (uint*)g_h0Q;
  uint* z1 = (uint*)g_h1Q;
  for (int i = idx; i < 2 * 64 * 128 * 4; i += n) { z0[i] = 0u; z1[i] = 0u; }
  for (int t = idx; t < T; t += n) out[BATCH * T * SSZ + t] = (float)t * 0.1f;
  for (int i = idx; i < 512 * 8 * CPAD; i += n) g_cnt[i] = 0;
}

// ---------------- Wcomb = 0.1 * W0s @ Wfc ----------------
__global__ void wcomb_kernel(const float* __restrict__ Wih0, const float* __restrict__ Wfc) {
  int idx = blockIdx.x * blockDim.x + threadIdx.x;
  int row = idx >> 9, k = idx & (HID - 1);
  float a = 0.f;
#pragma unroll
  for (int m = 0; m < SSZ; m++) a += Wih0[row * (XSZ + SSZ) + XSZ + m] * Wfc[m * HID + k];
  g_Wcomb[idx] = 0.1f * a;
}

// ---------------- persistent RNN kernel ----------------
__global__ __launch_bounds__(BT, 4) void persist_kernel(
    const float* __restrict__ x,    const float* __restrict__ s0,
    const float* __restrict__ Wih0, const float* __restrict__ Whh0,
    const float* __restrict__ bih0, const float* __restrict__ bhh0,
    const float* __restrict__ Wih1, const float* __restrict__ Whh1,
    const float* __restrict__ bih1, const float* __restrict__ bhh1,
    const float* __restrict__ Wfc,  const float* __restrict__ bfc,
    float* __restrict__ out, int T)
{
  __shared__ uint  lwT[4][256][8];    // [mat][kpair][row]: 0:Whh0 1:Wcomb 2:W1a 3:W1b
  __shared__ float gbuf[8][8][128];   // slots 0-3: Whh0 partials (B->next A); 4-7: Wcomb(A)/W1a(B)
  __shared__ float gbuf1[4][8][128];  // W1b partials (A -> epilogue B)
  __shared__ float sbase[8][128];     // x.W0x + biases
  __shared__ float c0s[2][128], c1s[2][128];
  __shared__ uint  wfcP[16][268];     // Wfc f16 pairs, padded rows
  __shared__ float b1s[8], ucs[8];
  __shared__ int   rel[2];            // LDS release words (even/odd pid)

  const int bk  = blockIdx.x;
  const int tid = threadIdx.x;
  const int ks  = tid >> 7;        // K-slice 0..7 (0-3: h0-K / phase B, 4-7: h1-K / phase A)
  const int b   = tid & 127;       // batch column
  const int q0  = (ks & 3) * 16;   // uint4-row base of this K-slice
  const int kp0 = (ks & 3) * 64;   // kpair base

  if (tid == 0) { rel[0] = -1; rel[1] = -1; }

  // ---- stage weights to LDS as f16 pairs (transposed: [kpair][row]) ----
  for (int e = tid; e < 4 * 256 * 8; e += BT) {
    int mat = e >> 11, kp = (e >> 3) & 255, r = e & 7;
    int row = (r >> 1) * HID + 2 * bk + (r & 1);
    const float* src = (mat == 0) ? &Whh0[row * HID]
                     : (mat == 1) ? &g_Wcomb[row * HID]
                     : (mat == 2) ? &Wih1[row * HID] : &Whh1[row * HID];
    lwT[mat][kp][r] = pack_f16(src[2 * kp], src[2 * kp + 1]);
  }
  for (int e = tid; e < 16 * 256; e += BT) {
    int fs_ = e >> 8, kp = e & 255;
    wfcP[fs_][kp] = pack_f16(Wfc[fs_ * HID + 2 * kp], Wfc[fs_ * HID + 2 * kp + 1]);
  }
  // ---- zero gbuf[0..3] (Whh0 partials for t=0: h0_{-1} = 0) ----
  for (int e = tid; e < 4 * 8 * 128; e += BT) ((float*)gbuf)[e] = 0.f;
  // ---- sbase = x.W0x + biases ----
  {
    int r = tid >> 7, bb = tid & 127;
    int row = (r >> 1) * HID + 2 * bk + (r & 1);
    float a = bih0[row] + bhh0[row];
    const float* wr = Wih0 + row * (XSZ + SSZ);
#pragma unroll 4
    for (int k = 0; k < XSZ; k++) a = fmaf(wr[k], x[bb * XSZ + k], a);
    sbase[r][bb] = a;
  }
  if (tid < 8) {
    int row = (tid >> 1) * HID + 2 * bk + (tid & 1);
    b1s[tid] = bih1[row] + bhh1[row];
    float uc = 0.f;
    const float* ws = Wih0 + row * (XSZ + SSZ) + XSZ;
#pragma unroll
    for (int m = 0; m < SSZ; m++) uc = fmaf(ws[m], bfc[m], uc);
    ucs[tid] = 0.1f * uc;
  }
  __syncthreads();

  // ---- per-batch carried state (tid<128): u = W0s.s0 - uconst ; c = 0 ----
  float u[8];
  if (tid < 128) {
#pragma unroll
    for (int r = 0; r < 8; r++) {
      int row = (r >> 1) * HID + 2 * bk + (r & 1);
      const float* ws = Wih0 + row * (XSZ + SSZ) + XSZ;
      float a = 0.f;
#pragma unroll
      for (int m = 0; m < SSZ; m++) a = fmaf(ws[m], s0[b * SSZ + m], a);
      u[r] = a - ucs[r];
    }
    c0s[0][b] = 0.f; c0s[1][b] = 0.f;
    c1s[0][b] = 0.f; c1s[1][b] = 0.f;
  }

  // ---- fc lane state (wave 15 of blocks 128..255; one batch row each) ----
  const bool fcw = (bk >= 128) && ((tid >> 6) == 15);
  const int  fb = bk - 128, lane = tid & 63, fs = lane & 15, fq = lane >> 4;
  float s_reg = 0.f, bfcj = 0.f;
  if (fcw && lane < SSZ) { s_reg = s0[fb * SSZ + lane]; bfcj = bfc[lane]; }

  auto fc_step = [&](int tt, const uint4* h1base) {
    const ulong64* hp = (const ulong64*)(h1base + fq * 16 * 128 + fb);
    ulong64 lo[16], hi[16];
#pragma unroll
    for (int i = 0; i < 16; ++i) {
      lo[i] = AL8(hp + i * 256);
      hi[i] = AL8(hp + i * 256 + 1);
    }
    const uint4* wp = (const uint4*)&wfcP[fs][fq * 64];
    float acc = 0.f;
#pragma unroll
    for (int i = 0; i < 16; ++i) {
      uint4 w = wp[i];
      acc = fdot2((uint)lo[i],         w.x, acc);
      acc = fdot2((uint)(lo[i] >> 32), w.y, acc);
      acc = fdot2((uint)hi[i],         w.z, acc);
      acc = fdot2((uint)(hi[i] >> 32), w.w, acc);
    }
    acc += __shfl_xor(acc, 16);
    acc += __shfl_xor(acc, 32);
    if (lane < SSZ) {
      float so = acc + bfcj;
      s_reg += 0.1f * so;
      out[fb * (T * SSZ) + tt * SSZ + fs] = s_reg;
      out[BATCH * T * SSZ + T + fb * (T * SSZ) + tt * SSZ + fs] = so;
    }
  };

  int p = 0;
  for (int t = 0; t < T; ++t) {
    // ===== phase A : waves 8-15 dual-dot on h1_{t-1}: Wcomb->gbuf[4..7], W1b->gbuf1 =====
    if (ks >= 4) {
      if (t > 0) group_wait(2 * t, 8, tid, rel);          // h1_{t-1} ready
      float accA[8] = {0,0,0,0,0,0,0,0}, accB[8] = {0,0,0,0,0,0,0,0};
      dots16x2(g_h1Q[p] + q0 * 128 + b, &lwT[1][kp0][0], &lwT[3][kp0][0], accA, accB);
#pragma unroll
      for (int r = 0; r < 8; r++) { gbuf[ks][r][b] = accA[r]; gbuf1[ks - 4][r][b] = accB[r]; }
    }
    __syncthreads();
    // ===== epilogue A (tid<128): gates0_t -> h0_t =====
    if (tid < 128) {
      float pre[8];
#pragma unroll
      for (int r = 0; r < 8; r++) {
        float s1 = gbuf[0][r][b] + gbuf[1][r][b] + gbuf[2][r][b] + gbuf[3][r][b];  // Whh0.h0_{t-1}
        float s2 = gbuf[4][r][b] + gbuf[5][r][b] + gbuf[6][r][b] + gbuf[7][r][b];  // Wcomb.h1_{t-1}
        u[r] += s2 + ucs[r];
        pre[r] = sbase[r][b] + s1 + u[r];
      }
      float h[2];
#pragma unroll
      for (int jj = 0; jj < 2; jj++) {
        float c = c0s[jj][b];
        c = sigf(pre[2 + jj]) * c + sigf(pre[0 + jj]) * tanh_fast(pre[4 + jj]);
        c0s[jj][b] = c;
        h[jj] = sigf(pre[6 + jj]) * tanh_fast(c);
      }
      AS4(((uint*)&g_h0Q[p ^ 1][(bk >> 2) * 128 + b]) + (bk & 3), pack_f16(h[0], h[1]));
      asm volatile("s_waitcnt vmcnt(0)" ::: "memory");    // h0 store at coherence point
      if ((tid & 63) == 0)
        __hip_atomic_fetch_add(&g_cnt[((2 * t + 1) * 8 + (bk & 7)) * CPAD], 1,
                               __ATOMIC_RELAXED, __HIP_MEMORY_SCOPE_AGENT);
    }
    __syncthreads();
    // ===== phase B : waves 0-7 dual-dot on h0_t: W1a->gbuf[4..7], Whh0->gbuf[0..3] =====
    if (ks < 4) {
      group_wait(2 * t + 1, 0, tid, rel);                 // h0_t ready
      float accA[8] = {0,0,0,0,0,0,0,0}, accB[8] = {0,0,0,0,0,0,0,0};
      dots16x2(g_h0Q[p ^ 1] + q0 * 128 + b, &lwT[2][kp0][0], &lwT[0][kp0][0], accA, accB);
#pragma unroll
      for (int r = 0; r < 8; r++) { gbuf[4 + ks][r][b] = accA[r]; gbuf[ks][r][b] = accB[r]; }
    } else {
      if (fcw && t > 0) fc_step(t - 1, g_h1Q[p]);         // fc for step t-1 in phase-B slack
    }
    __syncthreads();
    // ===== epilogue B (tid<128): gates1_t -> h1_t =====
    if (tid < 128) {
      float pre[8];
#pragma unroll
      for (int r = 0; r < 8; r++) {
        float s1 = gbuf[4][r][b] + gbuf[5][r][b] + gbuf[6][r][b] + gbuf[7][r][b];   // W1a.h0_t
        float s2 = gbuf1[0][r][b] + gbuf1[1][r][b] + gbuf1[2][r][b] + gbuf1[3][r][b]; // W1b.h1_{t-1}
        pre[r] = b1s[r] + s1 + s2;
      }
      float h[2];
#pragma unroll
      for (int jj = 0; jj < 2; jj++) {
        float c = c1s[jj][b];
        c = sigf(pre[2 + jj]) * c + sigf(pre[0 + jj]) * tanh_fast(pre[4 + jj]);
        c1s[jj][b] = c;
        h[jj] = sigf(pre[6 + jj]) * tanh_fast(c);
      }
      AS4(((uint*)&g_h1Q[p ^ 1][(bk >> 2) * 128 + b]) + (bk & 3), pack_f16(h[0], h[1]));
      asm volatile("s_waitcnt vmcnt(0)" ::: "memory");    // h1 store at coherence point
      if ((tid & 63) == 0)
        __hip_atomic_fetch_add(&g_cnt[((2 * t + 2) * 8 + (bk & 7)) * CPAD], 1,
                               __ATOMIC_RELAXED, __HIP_MEMORY_SCOPE_AGENT);
    }
    __syncthreads();
    p ^= 1;
  }

  // ---- final fc for step T-1 ----
  if (fcw) {
    cnt_wait(2 * T);
    fc_step(T - 1, g_h1Q[p]);
  }
}

extern "C" void kernel_launch(void* const* d_in, const int* in_sizes, int n_in,
                              void* d_out, int out_size, void* d_ws, size_t ws_size,
                              hipStream_t stream) {
  const float* x    = (const float*)d_in[0];
  const float* s0   = (const float*)d_in[1];
  const float* Wih0 = (const float*)d_in[2];
  const float* Whh0 = (const float*)d_in[3];
  const float* bih0 = (const float*)d_in[4];
  const float* bhh0 = (const float*)d_in[5];
  const float* Wih1 = (const float*)d_in[6];
  const float* Whh1 = (const float*)d_in[7];
  const float* bih1 = (const float*)d_in[8];
  const float* bhh1 = (const float*)d_in[9];
  const float* Wfc  = (const float*)d_in[10];
  const float* bfc  = (const float*)d_in[11];
  float* out = (float*)d_out;

  const int T = out_size / (2 * BATCH * SSZ + 1);

  setup_kernel<<<64, 256, 0, stream>>>(out, T);
  wcomb_kernel<<<(4 * HID * HID) / 256, 256, 0, stream>>>(Wih0, Wfc);
  persist_kernel<<<NB, BT, 0, stream>>>(x, s0, Wih0, Whh0, bih0, bhh0,
                                        Wih1, Whh1, bih1, bhh1, Wfc, bfc, out, T);
}